// Round 1
// baseline (243.281 us; speedup 1.0000x reference)
//
#include <hip/hip_runtime.h>
#include <hip/hip_bf16.h>
#include <stdint.h>

using bf16   = __bf16;
using bf16x8 = __attribute__((ext_vector_type(8))) __bf16;
using f32x4  = __attribute__((ext_vector_type(4))) float;

#define NN  2048   // nodes
#define DD  16     // embedding dim
#define BB  64     // batch
#define CC  64     // channels (in == out)
#define BCC 4096   // BB*CC

// ---------------- K1: A = softmax(relu(E E^T)) row-wise, bf16 out ----------
__global__ __launch_bounds__(256) void k_softmax(const float* __restrict__ E,
                                                 bf16* __restrict__ A) {
  const int n = blockIdx.x;
  const int t = threadIdx.x;
  float en[DD];
#pragma unroll
  for (int d = 0; d < DD; ++d) en[d] = E[(size_t)n * DD + d];

  float r[8];
  float mx = 0.0f;
#pragma unroll
  for (int j = 0; j < 8; ++j) {
    const int m = t + 256 * j;
    const float4* ep = (const float4*)(E + (size_t)m * DD);
    float4 p0 = ep[0], p1 = ep[1], p2 = ep[2], p3 = ep[3];
    float s = p0.x*en[0] + p0.y*en[1] + p0.z*en[2] + p0.w*en[3]
            + p1.x*en[4] + p1.y*en[5] + p1.z*en[6] + p1.w*en[7]
            + p2.x*en[8] + p2.y*en[9] + p2.z*en[10] + p2.w*en[11]
            + p3.x*en[12] + p3.y*en[13] + p3.z*en[14] + p3.w*en[15];
    s = fmaxf(s, 0.0f);
    r[j] = s;
    mx = fmaxf(mx, s);
  }
  __shared__ float red[256];
  red[t] = mx;
  __syncthreads();
  for (int off = 128; off > 0; off >>= 1) {
    if (t < off) red[t] = fmaxf(red[t], red[t + off]);
    __syncthreads();
  }
  mx = red[0];
  __syncthreads();
  float ex[8], sum = 0.0f;
#pragma unroll
  for (int j = 0; j < 8; ++j) { ex[j] = __expf(r[j] - mx); sum += ex[j]; }
  red[t] = sum;
  __syncthreads();
  for (int off = 128; off > 0; off >>= 1) {
    if (t < off) red[t] += red[t + off];
    __syncthreads();
  }
  const float inv = 1.0f / red[0];
#pragma unroll
  for (int j = 0; j < 8; ++j)
    A[(size_t)n * NN + t + 256 * j] = (bf16)(ex[j] * inv);
}

// ---------------- K1b: AT = A^T (bf16 -> bf16, 64x64 tiles) ----------------
__global__ __launch_bounds__(256) void k_transpose(const bf16* __restrict__ A,
                                                   bf16* __restrict__ AT) {
  __shared__ bf16 tile[64 * 68];
  const int bx = blockIdx.x, by = blockIdx.y;  // col-tile, row-tile
  const int t = threadIdx.x;
  const int r0 = by * 64, c0 = bx * 64;
#pragma unroll
  for (int j = 0; j < 16; ++j) {
    const int q = t + 256 * j;
    const int r = q >> 6, c = q & 63;
    tile[r * 68 + c] = A[(size_t)(r0 + r) * NN + c0 + c];
  }
  __syncthreads();
#pragma unroll
  for (int j = 0; j < 16; ++j) {
    const int q = t + 256 * j;
    const int rr = q >> 6, cc = q & 63;  // write row = c0+rr, col = r0+cc
    AT[(size_t)(c0 + rr) * NN + r0 + cc] = tile[cc * 68 + rr];
  }
}

// ---------------- K3: XrT[b*64+i][m] = bf16(x[b][m][i]) --------------------
__global__ __launch_bounds__(256) void k_build_xrt(const float* __restrict__ x,
                                                   bf16* __restrict__ XrT) {
  __shared__ bf16 tile[64 * 68];  // [m][i]
  const int b = blockIdx.x;       // 0..63
  const int m0 = blockIdx.y * 64; // 0..2047
  const int t = threadIdx.x;
#pragma unroll
  for (int j = 0; j < 16; ++j) {
    const int q = t + 256 * j;
    const int m = q >> 6, i = q & 63;
    tile[m * 68 + i] = (bf16)x[((size_t)b * NN + m0 + m) * CC + i];
  }
  __syncthreads();
#pragma unroll
  for (int j = 0; j < 16; ++j) {
    const int q = t + 256 * j;
    const int i = q >> 6, m = q & 63;
    XrT[((size_t)b * CC + i) * NN + m0 + m] = tile[m * 68 + i];
  }
}

// ---------------- GEMM (B^T form): C[m][n] = sum_k L[m][k]*R[n][k] ---------
// 128x128 tile, BK=64, 4 waves (2x2), 4x4 16x16x32 MFMA tiles per wave.
// EPI==1: C = 2*acc - I (T2 epilogue).
template <int EPI>
__global__ __launch_bounds__(256) void k_gemm_bt(const bf16* __restrict__ L,
                                                 const bf16* __restrict__ R,
                                                 bf16* __restrict__ C,
                                                 int M, int Nc, int K) {
  __shared__ uint4 lds[2048];  // [0..1023]=As 128x64 bf16, [1024..2047]=Rs
  const int t = threadIdx.x;
  const int lane = t & 63, w = t >> 6;
  const int wm = w & 1, wn = w >> 1;
  const int h = lane >> 4;
  const int m0 = blockIdx.y * 128, n0 = blockIdx.x * 128;

  f32x4 acc[4][4];
  const f32x4 zz = {0.f, 0.f, 0.f, 0.f};
#pragma unroll
  for (int mt = 0; mt < 4; ++mt)
#pragma unroll
    for (int nt = 0; nt < 4; ++nt) acc[mt][nt] = zz;

  const bf16x8* Asv = (const bf16x8*)lds;
  const bf16x8* Rsv = (const bf16x8*)(lds + 1024);

  for (int kt = 0; kt < K; kt += 64) {
    // stage 128x64 of L and R (reg->LDS), XOR-swizzled 16B columns
#pragma unroll
    for (int c = 0; c < 4; ++c) {
      const int q = t + 256 * c;          // 0..1023
      const int row = q >> 3, col4 = q & 7;
      const int sw = (row << 3) | (col4 ^ (row & 7));
      lds[sw]        = *(const uint4*)(L + (size_t)(m0 + row) * K + kt + (col4 << 3));
      lds[1024 + sw] = *(const uint4*)(R + (size_t)(n0 + row) * K + kt + (col4 << 3));
    }
    __syncthreads();
#pragma unroll
    for (int kk = 0; kk < 2; ++kk) {
      bf16x8 af[4], bfr[4];
#pragma unroll
      for (int mt = 0; mt < 4; ++mt) {
        const int row = wm * 64 + mt * 16 + (lane & 15);
        af[mt] = Asv[(row << 3) | ((kk * 4 + h) ^ (row & 7))];
      }
#pragma unroll
      for (int nt = 0; nt < 4; ++nt) {
        const int row = wn * 64 + nt * 16 + (lane & 15);
        bfr[nt] = Rsv[(row << 3) | ((kk * 4 + h) ^ (row & 7))];
      }
#pragma unroll
      for (int mt = 0; mt < 4; ++mt)
#pragma unroll
        for (int nt = 0; nt < 4; ++nt)
          acc[mt][nt] = __builtin_amdgcn_mfma_f32_16x16x32_bf16(
              af[mt], bfr[nt], acc[mt][nt], 0, 0, 0);
    }
    __syncthreads();
  }
  // epilogue: C/D layout col = lane&15, row = 4*(lane>>4)+r
#pragma unroll
  for (int mt = 0; mt < 4; ++mt)
#pragma unroll
    for (int nt = 0; nt < 4; ++nt)
#pragma unroll
      for (int r = 0; r < 4; ++r) {
        const int rg = m0 + wm * 64 + mt * 16 + 4 * h + r;
        const int cg = n0 + wn * 64 + nt * 16 + (lane & 15);
        float v = acc[mt][nt][r];
        if (EPI) v = 2.0f * v - (rg == cg ? 1.0f : 0.0f);
        C[(size_t)rg * Nc + cg] = (bf16)v;
      }
}

// ---------------- K5: per-node weight-gen + [64x192]@[192x64] MFMA ---------
__global__ __launch_bounds__(256) void k_node(const float* __restrict__ x,
                                              const float* __restrict__ E,
                                              const float* __restrict__ Wp,
                                              const float* __restrict__ bp,
                                              const bf16* __restrict__ xg1,
                                              const bf16* __restrict__ xg2,
                                              float* __restrict__ out) {
  const int n = blockIdx.x;
  const int t = threadIdx.x;
  __shared__ alignas(16) bf16 sW[64 * 200];  // [o][r], r = k*64+i, pad 200
  __shared__ float sbias[64];

  float en[DD];
#pragma unroll
  for (int d = 0; d < DD; ++d) en[d] = E[(size_t)n * DD + d];

  // weight gen: W[r][o] = sum_d en[d] * Wp[d][e], e = r*64+o; store at sW[o][r]
#pragma unroll 2
  for (int c = 0; c < 48; ++c) {
    const int e = t + 256 * c;  // 0..12287
    float a = 0.0f;
#pragma unroll
    for (int d = 0; d < DD; ++d) a += en[d] * Wp[(size_t)d * 12288 + e];
    sW[(e & 63) * 200 + (e >> 6)] = (bf16)a;
  }
  if (t < 64) {
    float a = 0.0f;
#pragma unroll
    for (int d = 0; d < DD; ++d) a += en[d] * bp[d * 64 + t];
    sbias[t] = a;
  }
  __syncthreads();

  const int lane = t & 63, w = t >> 6;
  const int h = lane >> 4;
  const int brow = w * 16 + (lane & 15);  // batch row this lane feeds (A operand)
  f32x4 acc[4];
  const f32x4 zz = {0.f, 0.f, 0.f, 0.f};
#pragma unroll
  for (int nt = 0; nt < 4; ++nt) acc[nt] = zz;

#pragma unroll
  for (int s = 0; s < 6; ++s) {       // k-steps of 32 over r=0..191
    const int r0 = s * 32 + h * 8;
    bf16x8 afr;
    if (s < 2) {                      // k=0: identity support, read x f32
      const float4* xp = (const float4*)(x + ((size_t)brow * NN + n) * CC + r0);
      float4 u = xp[0], v4 = xp[1];
      afr[0] = (bf16)u.x;  afr[1] = (bf16)u.y;  afr[2] = (bf16)u.z;  afr[3] = (bf16)u.w;
      afr[4] = (bf16)v4.x; afr[5] = (bf16)v4.y; afr[6] = (bf16)v4.z; afr[7] = (bf16)v4.w;
    } else if (s < 4) {
      afr = *(const bf16x8*)(xg1 + (size_t)n * BCC + brow * CC + (r0 - 64));
    } else {
      afr = *(const bf16x8*)(xg2 + (size_t)n * BCC + brow * CC + (r0 - 128));
    }
#pragma unroll
    for (int nt = 0; nt < 4; ++nt) {
      const bf16x8 bfr = *(const bf16x8*)(sW + (nt * 16 + (lane & 15)) * 200 + r0);
      acc[nt] = __builtin_amdgcn_mfma_f32_16x16x32_bf16(afr, bfr, acc[nt], 0, 0, 0);
    }
  }
#pragma unroll
  for (int nt = 0; nt < 4; ++nt)
#pragma unroll
    for (int r = 0; r < 4; ++r) {
      const int b = w * 16 + 4 * h + r;
      const int o = nt * 16 + (lane & 15);
      out[((size_t)b * NN + n) * CC + o] = acc[nt][r] + sbias[o];
    }
}

extern "C" void kernel_launch(void* const* d_in, const int* in_sizes, int n_in,
                              void* d_out, int out_size, void* d_ws, size_t ws_size,
                              hipStream_t stream) {
  const float* x  = (const float*)d_in[0];   // [64,2048,64]
  const float* E  = (const float*)d_in[1];   // [2048,16]
  const float* Wp = (const float*)d_in[2];   // [16,3,64,64]
  const float* bp = (const float*)d_in[3];   // [16,64]
  float* out = (float*)d_out;                // [64,2048,64]

  char* ws = (char*)d_ws;
  // layout (bytes): A:0-8M, T2:8-16M, XrT:16-32M, xg1:32-48M, xg2:48-64M,
  // AT:56-64M (aliases tail of xg2 -- AT is dead before xg2 is written).
  bf16* A   = (bf16*)(ws);
  bf16* T2  = (bf16*)(ws + (size_t)(1 << 23));
  bf16* XrT = (bf16*)(ws + (size_t)(1 << 24));
  bf16* xg1 = (bf16*)(ws + (size_t)(1 << 25));
  bf16* xg2 = (bf16*)(ws + (size_t)(3 << 24));
  bf16* AT  = (bf16*)(ws + (size_t)(7 << 23));

  k_softmax<<<NN, 256, 0, stream>>>(E, A);
  k_transpose<<<dim3(32, 32), 256, 0, stream>>>(A, AT);
  k_build_xrt<<<dim3(64, 32), 256, 0, stream>>>(x, XrT);
  // T2 = 2*A@A - I   (L=A [n][m], R=AT [c][m])
  k_gemm_bt<1><<<dim3(16, 16), 256, 0, stream>>>(A, AT, T2, NN, NN, NN);
  // xg1[n][c] = sum_m A[n][m] * XrT[c][m]
  k_gemm_bt<0><<<dim3(32, 16), 256, 0, stream>>>(A, XrT, xg1, NN, BCC, NN);
  // xg2[n][c] = sum_m T2[n][m] * XrT[c][m]
  k_gemm_bt<0><<<dim3(32, 16), 256, 0, stream>>>(T2, XrT, xg2, NN, BCC, NN);
  k_node<<<NN, 256, 0, stream>>>(x, E, Wp, bp, xg1, xg2, out);
}